// Round 14
// baseline (144.958 us; speedup 1.0000x reference)
//
#include <hip/hip_runtime.h>

#define FFT_N 4096
#define NT    256
#define PAIRS 4   // row-pairs per block; grid = 8192/(2*4) = 1024 = 4 blocks/CU exactly
// skew in 8-byte units: +1 per 16; all stage patterns conflict-free for b64
#define SK(i) ((i) + ((i) >> 4))
// base-4 digit-reverse involution for 16: P(m) = ((m&3)<<2)|(m>>2)
#define PM(m) ((((m) & 3) << 2) | ((m) >> 2))

typedef float    cplx __attribute__((ext_vector_type(2)));  // (re, im) fp32 math
typedef _Float16 h4   __attribute__((ext_vector_type(4)));  // LDS: r0.re,r0.im,r1.re,r1.im

__device__ __forceinline__ cplx mkc(float re, float im) { cplx c; c.x = re; c.y = im; return c; }
__device__ __forceinline__ h4 packh(cplx a, cplx b) {
    h4 v; v.x = (_Float16)a.x; v.y = (_Float16)a.y; v.z = (_Float16)b.x; v.w = (_Float16)b.y;
    return v;
}
__device__ __forceinline__ cplx cmul(cplx a, cplx b) {
    return mkc(a.x * b.x - a.y * b.y, a.x * b.y + a.y * b.x);
}
__device__ __forceinline__ cplx cmulc(cplx a, cplx b) {  // a * conj(b)
    return mkc(a.x * b.x + a.y * b.y, a.y * b.x - a.x * b.y);
}

// In-place 16-point DFT via two radix-4 layers (math verified r6/r12/r13).
// PERMIN=false: natural in, slot m holds freq PM(m). PERMIN=true: mirrored.
template <int SGN, bool PERMIN>
__device__ __forceinline__ void ip16(cplx* x) {
    const float S = (float)SGN;
    const float C1 = 0.92387953251128675613f;   // cos(pi/8)
    const float S1 = 0.38268343236508977173f;   // sin(pi/8)
    const float R2 = 0.70710678118654752440f;   // sqrt(2)/2
#define BF4(i0, i1, i2, i3) do { \
        cplx x0 = x[i0], x1 = x[i1], x2 = x[i2], x3 = x[i3]; \
        cplx t0 = x0 + x2, t1 = x0 - x2; \
        cplx t2 = x1 + x3, t3 = x1 - x3; \
        cplx it3 = mkc(-S * t3.y, S * t3.x); \
        x[i0] = t0 + t2; x[i1] = t1 + it3; \
        x[i2] = t0 - t2; x[i3] = t1 - it3; \
    } while (0)
    if (!PERMIN) { BF4(0, 4, 8, 12); BF4(1, 5, 9, 13); BF4(2, 6, 10, 14); BF4(3, 7, 11, 15); }
    else         { BF4(0, 1, 2, 3);  BF4(4, 5, 6, 7);  BF4(8, 9, 10, 11); BF4(12, 13, 14, 15); }
    const cplx w1 = mkc(C1, S * S1), w2 = mkc(R2, S * R2), w3 = mkc(S1, S * C1);
    const cplx w6 = mkc(-R2, S * R2), w9 = mkc(-C1, -S * S1);
    x[5]  = cmul(x[5],  w1);
    x[6]  = cmul(x[6],  w2);
    x[7]  = cmul(x[7],  w3);
    x[9]  = cmul(x[9],  w2);
    { cplx v = x[10]; x[10] = mkc(-S * v.y, S * v.x); }  // w4 = S*i
    x[11] = cmul(x[11], w6);
    x[13] = cmul(x[13], w3);
    x[14] = cmul(x[14], w6);
    x[15] = cmul(x[15], w9);
    if (!PERMIN) { BF4(0, 1, 2, 3);  BF4(4, 5, 6, 7);  BF4(8, 9, 10, 11); BF4(12, 13, 14, 15); }
    else         { BF4(0, 4, 8, 12); BF4(1, 5, 9, 13); BF4(2, 6, 10, 14); BF4(3, 7, 11, 15); }
#undef BF4
}

// d_ws: twA[4096] = W4096^(t*r) at [r*256+t]; twB[256] = W256^(j*r) at [r*16+j]
__global__ void twiddle_init(cplx* __restrict__ twA, cplx* __restrict__ twB) {
    int m = blockIdx.x * NT + threadIdx.x;   // 0..4351
    if (m >= 4352) return;
    float s, c;
    if (m < 4096) {
        int r = m >> 8, t = m & 255;
        sincosf(-6.28318530717958647692f * (float)(t * r) / 4096.0f, &s, &c);
        twA[m] = mkc(c, s);
    } else {
        int k = m - 4096;                    // k = r*16 + j
        int r = k >> 4, j = k & 15;
        sincosf(-6.28318530717958647692f * (float)(j * r) / 256.0f, &s, &c);
        twB[k] = mkc(c, s);
    }
}

__global__ __launch_bounds__(NT) void circconv4096_kernel(
    const float* __restrict__ A, const float* __restrict__ Bv,
    float* __restrict__ O,
    const cplx* __restrict__ twA, const cplx* __restrict__ twB)
{
    // two rows per iteration, paired per-element as 4xf16 (8 B): 34.8 KB -> 4 blocks/CU
    __shared__ h4 Z[SK(4095) + 1];
    const int t = threadIdx.x;
    const int j = t & 15;
    const int base = ((t >> 4) << 8) + j;

    // persistent block: PAIRS row-pairs, pointers advance by 2 rows each iter
    const size_t pair0 = (size_t)blockIdx.x * PAIRS;
    const float* pa0 = A  + pair0 * 2 * FFT_N;
    const float* pb0 = Bv + pair0 * 2 * FFT_N;
    float*       po0 = O  + pair0 * 2 * FFT_N;

    cplx x0[16], x1[16];

    // ---- prologue: load pair 0 ----
#pragma unroll
    for (int q = 0; q < 16; ++q) { int g = t + 256 * q; x0[q] = mkc(pa0[g], pb0[g]); }
#pragma unroll
    for (int q = 0; q < 16; ++q) { int g = t + 256 * q + FFT_N; x1[q] = mkc(pa0[g], pb0[g]); }

#pragma unroll 1
    for (int p = 0; p < PAIRS; ++p) {
        // ---- fwd stage 1 (stride 256): data already in registers ----
        ip16<-1, false>(x0);
        ip16<-1, false>(x1);
#pragma unroll
        for (int m = 1; m < 16; ++m) {
            cplx w = twA[PM(m) * 256 + t];
            x0[m] = cmul(x0[m], w);
            x1[m] = cmul(x1[m], w);
        }
#pragma unroll
        for (int m = 0; m < 16; ++m) Z[SK(t + 256 * PM(m))] = packh(x0[m], x1[m]);
        __syncthreads();

        // ---- fwd stage 2 (stride 16, wave-private) ----
#pragma unroll
        for (int q = 0; q < 16; ++q) {
            h4 v = Z[SK(base + 16 * q)];
            x0[q] = mkc((float)v.x, (float)v.y); x1[q] = mkc((float)v.z, (float)v.w);
        }
        ip16<-1, false>(x0);
        ip16<-1, false>(x1);
#pragma unroll
        for (int m = 1; m < 16; ++m) {
            cplx w = twB[PM(m) * 16 + j];
            x0[m] = cmul(x0[m], w);
            x1[m] = cmul(x1[m], w);
        }
        __builtin_amdgcn_wave_barrier();
#pragma unroll
        for (int m = 0; m < 16; ++m) Z[SK(base + 16 * PM(m))] = packh(x0[m], x1[m]);
        __builtin_amdgcn_wave_barrier();

        // ---- fwd stage 3 (contig) + scaled square + inv stage 1 (contig) ----
        {
            const int b3 = t * 16;
            const float s = 1.0f / 8192.0f;   // fold /4096 (ifft) and /2 (imag trick)
#pragma unroll
            for (int q = 0; q < 16; ++q) {
                h4 v = Z[SK(b3 + q)];
                x0[q] = mkc((float)v.x, (float)v.y); x1[q] = mkc((float)v.z, (float)v.w);
            }
            ip16<-1, false>(x0);
#pragma unroll
            for (int m = 0; m < 16; ++m) {
                cplx z = x0[m];
                x0[m] = mkc((z.x * z.x - z.y * z.y) * s, 2.0f * s * z.x * z.y);
            }
            ip16<1, true>(x0);
            ip16<-1, false>(x1);
#pragma unroll
            for (int m = 0; m < 16; ++m) {
                cplx z = x1[m];
                x1[m] = mkc((z.x * z.x - z.y * z.y) * s, 2.0f * s * z.x * z.y);
            }
            ip16<1, true>(x1);
            __builtin_amdgcn_wave_barrier();
#pragma unroll
            for (int q = 0; q < 16; ++q) Z[SK(b3 + q)] = packh(x0[q], x1[q]);
            __builtin_amdgcn_wave_barrier();
        }

        // ---- inv stage 2 (stride 16, wave-private): conj twiddle, inverse dft ----
#pragma unroll
        for (int r = 0; r < 16; ++r) {
            h4 v = Z[SK(base + 16 * r)];
            x0[r] = mkc((float)v.x, (float)v.y); x1[r] = mkc((float)v.z, (float)v.w);
        }
#pragma unroll
        for (int r = 1; r < 16; ++r) {
            cplx w = twB[r * 16 + j];
            x0[r] = cmulc(x0[r], w);
            x1[r] = cmulc(x1[r], w);
        }
        ip16<1, false>(x0);
        ip16<1, false>(x1);
        __builtin_amdgcn_wave_barrier();
#pragma unroll
        for (int m = 0; m < 16; ++m) Z[SK(base + 16 * PM(m))] = packh(x0[m], x1[m]);
        __syncthreads();   // inv stage 3 reads are stride-256: cross-wave

        // ---- inv stage 3 reads ----
#pragma unroll
        for (int r = 0; r < 16; ++r) {
            h4 v = Z[SK(t + 256 * r)];
            x0[r] = mkc((float)v.x, (float)v.y); x1[r] = mkc((float)v.z, (float)v.w);
        }
        __syncthreads();   // all reads done: Z free for next iteration's fwd1 writes

        // ---- inv stage 3 compute + store, interleaved with next-pair prefetch ----
#pragma unroll
        for (int r = 1; r < 16; ++r) {
            cplx w = twA[r * 256 + t];
            x0[r] = cmulc(x0[r], w);
            x1[r] = cmulc(x1[r], w);
        }
        ip16<1, false>(x0);
#pragma unroll
        for (int m = 0; m < 16; ++m) po0[t + 256 * PM(m)] = x0[m].y;
        if (p + 1 < PAIRS) {
            // prefetch next pair's row0 into freed x0; latency hides under ip16(x1)
            const float* na = pa0 + 2 * FFT_N;
            const float* nb = pb0 + 2 * FFT_N;
#pragma unroll
            for (int q = 0; q < 16; ++q) { int g = t + 256 * q; x0[q] = mkc(na[g], nb[g]); }
        }
        ip16<1, false>(x1);
#pragma unroll
        for (int m = 0; m < 16; ++m) po0[t + 256 * PM(m) + FFT_N] = x1[m].y;
        if (p + 1 < PAIRS) {
            // prefetch next pair's row1; latency hides under next fwd1's ip16(x0)
            const float* na = pa0 + 2 * FFT_N;
            const float* nb = pb0 + 2 * FFT_N;
#pragma unroll
            for (int q = 0; q < 16; ++q) { int g = t + 256 * q + FFT_N; x1[q] = mkc(na[g], nb[g]); }
        }
        pa0 += 2 * FFT_N; pb0 += 2 * FFT_N; po0 += 2 * FFT_N;
    }
}

extern "C" void kernel_launch(void* const* d_in, const int* in_sizes, int n_in,
                              void* d_out, int out_size, void* d_ws, size_t ws_size,
                              hipStream_t stream) {
    const float* a = (const float*)d_in[0];
    const float* b = (const float*)d_in[1];
    float* out = (float*)d_out;
    cplx* twA = (cplx*)d_ws;              // 4096 cplx
    cplx* twB = twA + 4096;               // 256 cplx  (total 34 KB)
    const int B = in_sizes[0] / FFT_N;    // 8192 rows

    twiddle_init<<<17, NT, 0, stream>>>(twA, twB);            // 4352 entries
    circconv4096_kernel<<<B / (2 * PAIRS), NT, 0, stream>>>(a, b, out, twA, twB);
}

// Round 16
// 123.127 us; speedup vs baseline: 1.1773x; 1.1773x over previous
//
#include <hip/hip_runtime.h>

#define FFT_N 4096
#define NT    256
// skew in 4-byte units: +1 per 16; all stage patterns <=2-way (free) for b32
#define SK(i) ((i) + ((i) >> 4))
// base-4 digit-reverse involution for 16: P(m) = ((m&3)<<2)|(m>>2)
#define PM(m) ((((m) & 3) << 2) | ((m) >> 2))

typedef float  cplx __attribute__((ext_vector_type(2)));  // (re, im) fp32 math
typedef __fp16 h2   __attribute__((ext_vector_type(2)));  // LDS: (re, im) f16

__device__ __forceinline__ cplx mkc(float re, float im) { cplx c; c.x = re; c.y = im; return c; }
__device__ __forceinline__ h2 packh(cplx a) {
    return __builtin_amdgcn_cvt_pkrtz(a.x, a.y);   // one v_cvt_pkrtz_f16_f32
}
__device__ __forceinline__ cplx unpackh(h2 v) { return mkc((float)v.x, (float)v.y); }
__device__ __forceinline__ cplx cmul(cplx a, cplx b) {
    return mkc(a.x * b.x - a.y * b.y, a.x * b.y + a.y * b.x);
}
__device__ __forceinline__ cplx cmulc(cplx a, cplx b) {  // a * conj(b)
    return mkc(a.x * b.x + a.y * b.y, a.y * b.x - a.x * b.y);
}

// In-place 16-point DFT via two radix-4 layers (math verified r6/r12/r13).
// PERMIN=false: natural in, slot m holds freq PM(m). PERMIN=true: mirrored.
template <int SGN, bool PERMIN>
__device__ __forceinline__ void ip16(cplx* x) {
    const float S = (float)SGN;
    const float C1 = 0.92387953251128675613f;   // cos(pi/8)
    const float S1 = 0.38268343236508977173f;   // sin(pi/8)
    const float R2 = 0.70710678118654752440f;   // sqrt(2)/2
#define BF4(i0, i1, i2, i3) do { \
        cplx x0 = x[i0], x1 = x[i1], x2 = x[i2], x3 = x[i3]; \
        cplx t0 = x0 + x2, t1 = x0 - x2; \
        cplx t2 = x1 + x3, t3 = x1 - x3; \
        cplx it3 = mkc(-S * t3.y, S * t3.x); \
        x[i0] = t0 + t2; x[i1] = t1 + it3; \
        x[i2] = t0 - t2; x[i3] = t1 - it3; \
    } while (0)
    if (!PERMIN) { BF4(0, 4, 8, 12); BF4(1, 5, 9, 13); BF4(2, 6, 10, 14); BF4(3, 7, 11, 15); }
    else         { BF4(0, 1, 2, 3);  BF4(4, 5, 6, 7);  BF4(8, 9, 10, 11); BF4(12, 13, 14, 15); }
    const cplx w1 = mkc(C1, S * S1), w2 = mkc(R2, S * R2), w3 = mkc(S1, S * C1);
    const cplx w6 = mkc(-R2, S * R2), w9 = mkc(-C1, -S * S1);
    x[5]  = cmul(x[5],  w1);
    x[6]  = cmul(x[6],  w2);
    x[7]  = cmul(x[7],  w3);
    x[9]  = cmul(x[9],  w2);
    { cplx v = x[10]; x[10] = mkc(-S * v.y, S * v.x); }  // w4 = S*i
    x[11] = cmul(x[11], w6);
    x[13] = cmul(x[13], w3);
    x[14] = cmul(x[14], w6);
    x[15] = cmul(x[15], w9);
    if (!PERMIN) { BF4(0, 1, 2, 3);  BF4(4, 5, 6, 7);  BF4(8, 9, 10, 11); BF4(12, 13, 14, 15); }
    else         { BF4(0, 4, 8, 12); BF4(1, 5, 9, 13); BF4(2, 6, 10, 14); BF4(3, 7, 11, 15); }
#undef BF4
}

// d_ws: twA[4096] = W4096^(t*r) at [r*256+t]; twB[256] = W256^(j*r) at [r*16+j]
__global__ void twiddle_init(cplx* __restrict__ twA, cplx* __restrict__ twB) {
    int m = blockIdx.x * NT + threadIdx.x;   // 0..4351
    if (m >= 4352) return;
    float s, c;
    if (m < 4096) {
        int r = m >> 8, t = m & 255;
        sincosf(-6.28318530717958647692f * (float)(t * r) / 4096.0f, &s, &c);
        twA[m] = mkc(c, s);
    } else {
        int k = m - 4096;                    // k = r*16 + j
        int r = k >> 4, j = k & 15;
        sincosf(-6.28318530717958647692f * (float)(j * r) / 256.0f, &s, &c);
        twB[k] = mkc(c, s);
    }
}

__global__ __launch_bounds__(NT) void circconv4096_kernel(
    const float* __restrict__ A, const float* __restrict__ Bv,
    float* __restrict__ O,
    const cplx* __restrict__ twA, const cplx* __restrict__ twB)
{
    // ONE row per block, f16 LDS: 17.4 KB -> 8 blocks/CU (wave-limit), 100% theoretical occ
    __shared__ h2 Z[SK(4095) + 1];
    const int t = threadIdx.x;
    const size_t row = blockIdx.x;
    const float* a = A + row * FFT_N;
    const float* b = Bv + row * FFT_N;
    float* o = O + row * FFT_N;

    cplx x[16];

    // ---- fwd stage 1 (stride 256): coalesced load + dft + twiddle ----
#pragma unroll
    for (int q = 0; q < 16; ++q) { int g = t + 256 * q; x[q] = mkc(a[g], b[g]); }
    ip16<-1, false>(x);
#pragma unroll
    for (int m = 1; m < 16; ++m) x[m] = cmul(x[m], twA[PM(m) * 256 + t]);
#pragma unroll
    for (int m = 0; m < 16; ++m) Z[SK(t + 256 * PM(m))] = packh(x[m]);
    __syncthreads();

    // ---- middle stages wave-private: wave w owns elements [1024w, 1024w+1024) ----
    const int j = t & 15;
    const int base = ((t >> 4) << 8) + j;

    // ---- fwd stage 2 (stride 16) ----
#pragma unroll
    for (int q = 0; q < 16; ++q) x[q] = unpackh(Z[SK(base + 16 * q)]);
    ip16<-1, false>(x);
#pragma unroll
    for (int m = 1; m < 16; ++m) x[m] = cmul(x[m], twB[PM(m) * 16 + j]);
    __builtin_amdgcn_wave_barrier();
#pragma unroll
    for (int m = 0; m < 16; ++m) Z[SK(base + 16 * PM(m))] = packh(x[m]);
    __builtin_amdgcn_wave_barrier();

    // ---- fwd stage 3 (contig) + scaled square + inv stage 1 (contig) ----
    {
        const int b3 = t * 16;
        const float s = 1.0f / 8192.0f;   // fold /4096 (ifft) and /2 (imag trick) HERE
#pragma unroll
        for (int q = 0; q < 16; ++q) x[q] = unpackh(Z[SK(b3 + q)]);
        ip16<-1, false>(x);
#pragma unroll
        for (int m = 0; m < 16; ++m) {
            cplx z = x[m];
            x[m] = mkc((z.x * z.x - z.y * z.y) * s, 2.0f * s * z.x * z.y);  // Z^2 * s
        }
        ip16<1, true>(x);
        __builtin_amdgcn_wave_barrier();
#pragma unroll
        for (int q = 0; q < 16; ++q) Z[SK(b3 + q)] = packh(x[q]);
        __builtin_amdgcn_wave_barrier();
    }

    // ---- inv stage 2 (stride 16): conj twiddle, inverse dft ----
#pragma unroll
    for (int r = 0; r < 16; ++r) x[r] = unpackh(Z[SK(base + 16 * r)]);
#pragma unroll
    for (int r = 1; r < 16; ++r) x[r] = cmulc(x[r], twB[r * 16 + j]);
    ip16<1, false>(x);
    __builtin_amdgcn_wave_barrier();
#pragma unroll
    for (int m = 0; m < 16; ++m) Z[SK(base + 16 * PM(m))] = packh(x[m]);
    __syncthreads();   // next stage is stride-256: cross-wave

    // ---- inv stage 3 (stride 256) + coalesced store (normalization already folded) ----
#pragma unroll
    for (int r = 0; r < 16; ++r) x[r] = unpackh(Z[SK(t + 256 * r)]);
#pragma unroll
    for (int r = 1; r < 16; ++r) x[r] = cmulc(x[r], twA[r * 256 + t]);
    ip16<1, false>(x);
#pragma unroll
    for (int m = 0; m < 16; ++m) o[t + 256 * PM(m)] = x[m].y;
}

extern "C" void kernel_launch(void* const* d_in, const int* in_sizes, int n_in,
                              void* d_out, int out_size, void* d_ws, size_t ws_size,
                              hipStream_t stream) {
    const float* a = (const float*)d_in[0];
    const float* b = (const float*)d_in[1];
    float* out = (float*)d_out;
    cplx* twA = (cplx*)d_ws;              // 4096 cplx
    cplx* twB = twA + 4096;               // 256 cplx  (total 34 KB)
    const int B = in_sizes[0] / FFT_N;    // 8192 rows

    twiddle_init<<<17, NT, 0, stream>>>(twA, twB);        // 4352 entries
    circconv4096_kernel<<<B, NT, 0, stream>>>(a, b, out, twA, twB);
}

// Round 18
// 107.298 us; speedup vs baseline: 1.3510x; 1.1475x over previous
//
#include <hip/hip_runtime.h>

#define FFT_N 4096
#define NT    256
// skew in 16-byte units: +1 per 16 (r12-verified: conflicts ~1e6, negligible)
#define SK(i) ((i) + ((i) >> 4))
// base-4 digit-reverse involution for 16: P(m) = ((m&3)<<2)|(m>>2)
#define PM(m) ((((m) & 3) << 2) | ((m) >> 2))

typedef float f2 __attribute__((ext_vector_type(2)));  // lane = row: (row0, row1)
typedef float f4 __attribute__((ext_vector_type(4)));  // LDS: re0, re1, im0, im1

__device__ __forceinline__ f2 mk2(float a, float b) { f2 v; v.x = a; v.y = b; return v; }

// In-place 16-point DFT, SoA over rows: re[m]/im[m] are (row0,row1) pairs.
// Every add/sub/mul is a packed VOP3P op covering both rows.
// Identical math to the r6/r12/r13-verified ip16 (signs re-derived and checked).
// PERMIN=false: natural in, slot m holds freq PM(m). PERMIN=true: mirrored.
template <int SGN, bool PERMIN>
__device__ __forceinline__ void ip16(f2* re, f2* im) {
    const float C1 = 0.92387953251128675613f;   // cos(pi/8)
    const float S1 = 0.38268343236508977173f;   // sin(pi/8)
    const float R2 = 0.70710678118654752440f;   // sqrt(2)/2
    // BF4: x[i0..i3] radix-4 butterfly; S*i rotation = re/im swap + folded sign
#define BF4(i0, i1, i2, i3) do { \
        f2 t0r = re[i0] + re[i2], t0i = im[i0] + im[i2]; \
        f2 t1r = re[i0] - re[i2], t1i = im[i0] - im[i2]; \
        f2 t2r = re[i1] + re[i3], t2i = im[i1] + im[i3]; \
        f2 t3r = re[i1] - re[i3], t3i = im[i1] - im[i3]; \
        re[i0] = t0r + t2r; im[i0] = t0i + t2i; \
        re[i2] = t0r - t2r; im[i2] = t0i - t2i; \
        if (SGN < 0) { re[i1] = t1r + t3i; im[i1] = t1i - t3r; \
                       re[i3] = t1r - t3i; im[i3] = t1i + t3r; } \
        else         { re[i1] = t1r - t3i; im[i1] = t1i + t3r; \
                       re[i3] = t1r + t3i; im[i3] = t1i - t3r; } \
    } while (0)
    // x[m] *= (cr + i*S*ci), cr/ci compile-time floats, broadcast into both rows
#define TWM(m, cr, ci) do { \
        f2 rr_ = re[m], ii_ = im[m]; \
        if (SGN < 0) { re[m] = rr_ * (cr) + ii_ * (ci); im[m] = ii_ * (cr) - rr_ * (ci); } \
        else         { re[m] = rr_ * (cr) - ii_ * (ci); im[m] = ii_ * (cr) + rr_ * (ci); } \
    } while (0)
    if (!PERMIN) { BF4(0, 4, 8, 12); BF4(1, 5, 9, 13); BF4(2, 6, 10, 14); BF4(3, 7, 11, 15); }
    else         { BF4(0, 1, 2, 3);  BF4(4, 5, 6, 7);  BF4(8, 9, 10, 11); BF4(12, 13, 14, 15); }
    TWM(5,  C1, S1);    // w1
    TWM(6,  R2, R2);    // w2
    TWM(7,  S1, C1);    // w3
    TWM(9,  R2, R2);    // w2
    {   // x[10] *= S*i : re' = -S*im, im' = S*re
        f2 rr_ = re[10], ii_ = im[10];
        if (SGN < 0) { re[10] = ii_; im[10] = mk2(0.f, 0.f) - rr_; }
        else         { re[10] = mk2(0.f, 0.f) - ii_; im[10] = rr_; }
    }
    TWM(11, -R2, R2);   // w6
    TWM(13, S1, C1);    // w3
    TWM(14, -R2, R2);   // w6
    TWM(15, -C1, -S1);  // w9
    if (!PERMIN) { BF4(0, 1, 2, 3);  BF4(4, 5, 6, 7);  BF4(8, 9, 10, 11); BF4(12, 13, 14, 15); }
    else         { BF4(0, 4, 8, 12); BF4(1, 5, 9, 13); BF4(2, 6, 10, 14); BF4(3, 7, 11, 15); }
#undef BF4
#undef TWM
}

typedef float cplx __attribute__((ext_vector_type(2)));
// d_ws: twA[4096] = W4096^(t*r) at [r*256+t]; twB[256] = W256^(j*r) at [r*16+j]
__global__ void twiddle_init(cplx* __restrict__ twA, cplx* __restrict__ twB) {
    int m = blockIdx.x * NT + threadIdx.x;   // 0..4351
    if (m >= 4352) return;
    float s, c;
    if (m < 4096) {
        int r = m >> 8, t = m & 255;
        sincosf(-6.28318530717958647692f * (float)(t * r) / 4096.0f, &s, &c);
        cplx v; v.x = c; v.y = s; twA[m] = v;
    } else {
        int k = m - 4096;                    // k = r*16 + j
        int r = k >> 4, j = k & 15;
        sincosf(-6.28318530717958647692f * (float)(j * r) / 256.0f, &s, &c);
        cplx v; v.x = c; v.y = s; twB[k] = v;
    }
}

__global__ __launch_bounds__(NT) void circconv4096_kernel(
    const float* __restrict__ A, const float* __restrict__ Bv,
    float* __restrict__ O,
    const cplx* __restrict__ twA, const cplx* __restrict__ twB)
{
    // two rows per block, row-packed per element in one b128: 69.6 KB -> 2 blocks/CU
    __shared__ f4 Z[SK(4095) + 1];
    const int t = threadIdx.x;
    const size_t r0 = (size_t)blockIdx.x * 2;
    const float* a0 = A + r0 * FFT_N;
    const float* b0 = Bv + r0 * FFT_N;
    const float* a1 = a0 + FFT_N;
    const float* b1 = b0 + FFT_N;
    float* o0 = O + r0 * FFT_N;
    float* o1 = o0 + FFT_N;

    f2 re[16], im[16];

    // forward twiddle x[m] *= w ; inverse x[m] *= conj(w) — w scalar, broadcast
#define TWF(m, w) do { f2 rr_ = re[m], ii_ = im[m]; float wr_ = (w).x, wi_ = (w).y; \
        re[m] = rr_ * wr_ - ii_ * wi_; im[m] = rr_ * wi_ + ii_ * wr_; } while (0)
#define TWC(m, w) do { f2 rr_ = re[m], ii_ = im[m]; float wr_ = (w).x, wi_ = (w).y; \
        re[m] = rr_ * wr_ + ii_ * wi_; im[m] = ii_ * wr_ - rr_ * wi_; } while (0)

    // ---- fwd stage 1 (stride 256): coalesced loads, both rows ----
#pragma unroll
    for (int q = 0; q < 16; ++q) {
        int g = t + 256 * q;
        re[q] = mk2(a0[g], a1[g]);
        im[q] = mk2(b0[g], b1[g]);   // z = a + i*b per row
    }
    ip16<-1, false>(re, im);
#pragma unroll
    for (int m = 1; m < 16; ++m) { cplx w = twA[PM(m) * 256 + t]; TWF(m, w); }
#pragma unroll
    for (int m = 0; m < 16; ++m) {
        f4 v; v.x = re[m].x; v.y = re[m].y; v.z = im[m].x; v.w = im[m].y;
        Z[SK(t + 256 * PM(m))] = v;
    }
    __syncthreads();

    // ---- middle stages wave-private: wave w owns elements [1024w, 1024w+1024) ----
    const int j = t & 15;
    const int base = ((t >> 4) << 8) + j;

    // ---- fwd stage 2 (stride 16) ----
#pragma unroll
    for (int q = 0; q < 16; ++q) {
        f4 v = Z[SK(base + 16 * q)];
        re[q] = mk2(v.x, v.y); im[q] = mk2(v.z, v.w);
    }
    ip16<-1, false>(re, im);
#pragma unroll
    for (int m = 1; m < 16; ++m) { cplx w = twB[PM(m) * 16 + j]; TWF(m, w); }
    __builtin_amdgcn_wave_barrier();
#pragma unroll
    for (int m = 0; m < 16; ++m) {
        f4 v; v.x = re[m].x; v.y = re[m].y; v.z = im[m].x; v.w = im[m].y;
        Z[SK(base + 16 * PM(m))] = v;
    }
    __builtin_amdgcn_wave_barrier();

    // ---- fwd stage 3 (contig) + scaled square + inv stage 1 (contig) ----
    {
        const int b3 = t * 16;
        const float s = 1.0f / 8192.0f;   // fold /4096 (ifft) and /2 (imag trick)
#pragma unroll
        for (int q = 0; q < 16; ++q) {
            f4 v = Z[SK(b3 + q)];
            re[q] = mk2(v.x, v.y); im[q] = mk2(v.z, v.w);
        }
        ip16<-1, false>(re, im);
#pragma unroll
        for (int m = 0; m < 16; ++m) {
            f2 r = re[m], i = im[m];
            re[m] = (r * r - i * i) * s;      // (re^2 - im^2) * s, both rows
            im[m] = (r * i) * (2.0f * s);     // 2*s*re*im, both rows
        }
        ip16<1, true>(re, im);
        __builtin_amdgcn_wave_barrier();
#pragma unroll
        for (int q = 0; q < 16; ++q) {
            f4 v; v.x = re[q].x; v.y = re[q].y; v.z = im[q].x; v.w = im[q].y;
            Z[SK(b3 + q)] = v;
        }
        __builtin_amdgcn_wave_barrier();
    }

    // ---- inv stage 2 (stride 16): conj twiddle, inverse dft ----
#pragma unroll
    for (int q = 0; q < 16; ++q) {
        f4 v = Z[SK(base + 16 * q)];
        re[q] = mk2(v.x, v.y); im[q] = mk2(v.z, v.w);
    }
#pragma unroll
    for (int q = 1; q < 16; ++q) { cplx w = twB[q * 16 + j]; TWC(q, w); }
    ip16<1, false>(re, im);
    __builtin_amdgcn_wave_barrier();
#pragma unroll
    for (int m = 0; m < 16; ++m) {
        f4 v; v.x = re[m].x; v.y = re[m].y; v.z = im[m].x; v.w = im[m].y;
        Z[SK(base + 16 * PM(m))] = v;
    }
    __syncthreads();   // next stage is stride-256: cross-wave

    // ---- inv stage 3 (stride 256) + coalesced store (normalization folded) ----
#pragma unroll
    for (int q = 0; q < 16; ++q) {
        f4 v = Z[SK(t + 256 * q)];
        re[q] = mk2(v.x, v.y); im[q] = mk2(v.z, v.w);
    }
#pragma unroll
    for (int q = 1; q < 16; ++q) { cplx w = twA[q * 256 + t]; TWC(q, w); }
    ip16<1, false>(re, im);
#pragma unroll
    for (int m = 0; m < 16; ++m) {
        int idx = t + 256 * PM(m);
        o0[idx] = im[m].x;
        o1[idx] = im[m].y;
    }
#undef TWF
#undef TWC
}

extern "C" void kernel_launch(void* const* d_in, const int* in_sizes, int n_in,
                              void* d_out, int out_size, void* d_ws, size_t ws_size,
                              hipStream_t stream) {
    const float* a = (const float*)d_in[0];
    const float* b = (const float*)d_in[1];
    float* out = (float*)d_out;
    cplx* twA = (cplx*)d_ws;              // 4096 cplx
    cplx* twB = twA + 4096;               // 256 cplx  (total 34 KB)
    const int B = in_sizes[0] / FFT_N;    // 8192 rows

    twiddle_init<<<17, NT, 0, stream>>>(twA, twB);        // 4352 entries
    circconv4096_kernel<<<B / 2, NT, 0, stream>>>(a, b, out, twA, twB);
}

// Round 19
// 104.769 us; speedup vs baseline: 1.3836x; 1.0241x over previous
//
#include <hip/hip_runtime.h>

#define FFT_N 4096
#define NT    256
// skew in 8-byte units: +1 per 16 (r13-verified layout: conflicts ~0.5e6)
#define SK(i) ((i) + ((i) >> 4))
// base-4 digit-reverse involution for 16: P(m) = ((m&3)<<2)|(m>>2)
#define PM(m) ((((m) & 3) << 2) | ((m) >> 2))

typedef float  f2 __attribute__((ext_vector_type(2)));  // lane = row: (row0, row1)
typedef __fp16 h4 __attribute__((ext_vector_type(4)));  // LDS: re0, re1, im0, im1

__device__ __forceinline__ f2 mk2(float a, float b) { f2 v; v.x = a; v.y = b; return v; }
__device__ __forceinline__ h4 packh(f2 re, f2 im) {
    h4 v; v.x = (__fp16)re.x; v.y = (__fp16)re.y; v.z = (__fp16)im.x; v.w = (__fp16)im.y;
    return v;
}

// In-place 16-point DFT, SoA over rows: re[m]/im[m] are (row0,row1) pairs.
// Every add/sub/mul is a packed VOP3P op covering both rows (verified r18).
// PERMIN=false: natural in, slot m holds freq PM(m). PERMIN=true: mirrored.
template <int SGN, bool PERMIN>
__device__ __forceinline__ void ip16(f2* re, f2* im) {
    const float C1 = 0.92387953251128675613f;   // cos(pi/8)
    const float S1 = 0.38268343236508977173f;   // sin(pi/8)
    const float R2 = 0.70710678118654752440f;   // sqrt(2)/2
#define BF4(i0, i1, i2, i3) do { \
        f2 t0r = re[i0] + re[i2], t0i = im[i0] + im[i2]; \
        f2 t1r = re[i0] - re[i2], t1i = im[i0] - im[i2]; \
        f2 t2r = re[i1] + re[i3], t2i = im[i1] + im[i3]; \
        f2 t3r = re[i1] - re[i3], t3i = im[i1] - im[i3]; \
        re[i0] = t0r + t2r; im[i0] = t0i + t2i; \
        re[i2] = t0r - t2r; im[i2] = t0i - t2i; \
        if (SGN < 0) { re[i1] = t1r + t3i; im[i1] = t1i - t3r; \
                       re[i3] = t1r - t3i; im[i3] = t1i + t3r; } \
        else         { re[i1] = t1r - t3i; im[i1] = t1i + t3r; \
                       re[i3] = t1r + t3i; im[i3] = t1i - t3r; } \
    } while (0)
#define TWM(m, cr, ci) do { \
        f2 rr_ = re[m], ii_ = im[m]; \
        if (SGN < 0) { re[m] = rr_ * (cr) + ii_ * (ci); im[m] = ii_ * (cr) - rr_ * (ci); } \
        else         { re[m] = rr_ * (cr) - ii_ * (ci); im[m] = ii_ * (cr) + rr_ * (ci); } \
    } while (0)
    if (!PERMIN) { BF4(0, 4, 8, 12); BF4(1, 5, 9, 13); BF4(2, 6, 10, 14); BF4(3, 7, 11, 15); }
    else         { BF4(0, 1, 2, 3);  BF4(4, 5, 6, 7);  BF4(8, 9, 10, 11); BF4(12, 13, 14, 15); }
    TWM(5,  C1, S1);    // w1
    TWM(6,  R2, R2);    // w2
    TWM(7,  S1, C1);    // w3
    TWM(9,  R2, R2);    // w2
    {   // x[10] *= S*i : re' = -S*im, im' = S*re
        f2 rr_ = re[10], ii_ = im[10];
        if (SGN < 0) { re[10] = ii_; im[10] = mk2(0.f, 0.f) - rr_; }
        else         { re[10] = mk2(0.f, 0.f) - ii_; im[10] = rr_; }
    }
    TWM(11, -R2, R2);   // w6
    TWM(13, S1, C1);    // w3
    TWM(14, -R2, R2);   // w6
    TWM(15, -C1, -S1);  // w9
    if (!PERMIN) { BF4(0, 1, 2, 3);  BF4(4, 5, 6, 7);  BF4(8, 9, 10, 11); BF4(12, 13, 14, 15); }
    else         { BF4(0, 4, 8, 12); BF4(1, 5, 9, 13); BF4(2, 6, 10, 14); BF4(3, 7, 11, 15); }
#undef BF4
#undef TWM
}

typedef float cplx __attribute__((ext_vector_type(2)));
// d_ws: twA[4096] = W4096^(t*r) at [r*256+t]; twB[256] = W256^(j*r) at [r*16+j]
__global__ void twiddle_init(cplx* __restrict__ twA, cplx* __restrict__ twB) {
    int m = blockIdx.x * NT + threadIdx.x;   // 0..4351
    if (m >= 4352) return;
    float s, c;
    if (m < 4096) {
        int r = m >> 8, t = m & 255;
        sincosf(-6.28318530717958647692f * (float)(t * r) / 4096.0f, &s, &c);
        cplx v; v.x = c; v.y = s; twA[m] = v;
    } else {
        int k = m - 4096;                    // k = r*16 + j
        int r = k >> 4, j = k & 15;
        sincosf(-6.28318530717958647692f * (float)(j * r) / 256.0f, &s, &c);
        cplx v; v.x = c; v.y = s; twB[k] = v;
    }
}

__global__ __launch_bounds__(NT) void circconv4096_kernel(
    const float* __restrict__ A, const float* __restrict__ Bv,
    float* __restrict__ O,
    const cplx* __restrict__ twA, const cplx* __restrict__ twB)
{
    // two rows per block, row-packed 4xf16 per element (b64): 34.8 KB -> 4 blocks/CU
    __shared__ h4 Z[SK(4095) + 1];
    const int t = threadIdx.x;
    const size_t r0 = (size_t)blockIdx.x * 2;
    const float* a0 = A + r0 * FFT_N;
    const float* b0 = Bv + r0 * FFT_N;
    const float* a1 = a0 + FFT_N;
    const float* b1 = b0 + FFT_N;
    float* o0 = O + r0 * FFT_N;
    float* o1 = o0 + FFT_N;

    f2 re[16], im[16];

    // forward twiddle x[m] *= w ; inverse x[m] *= conj(w) — w scalar, broadcast
#define TWF(m, w) do { f2 rr_ = re[m], ii_ = im[m]; float wr_ = (w).x, wi_ = (w).y; \
        re[m] = rr_ * wr_ - ii_ * wi_; im[m] = rr_ * wi_ + ii_ * wr_; } while (0)
#define TWC(m, w) do { f2 rr_ = re[m], ii_ = im[m]; float wr_ = (w).x, wi_ = (w).y; \
        re[m] = rr_ * wr_ + ii_ * wi_; im[m] = ii_ * wr_ - rr_ * wi_; } while (0)

    // ---- fwd stage 1 (stride 256): coalesced loads, both rows ----
#pragma unroll
    for (int q = 0; q < 16; ++q) {
        int g = t + 256 * q;
        re[q] = mk2(a0[g], a1[g]);
        im[q] = mk2(b0[g], b1[g]);   // z = a + i*b per row
    }
    ip16<-1, false>(re, im);
#pragma unroll
    for (int m = 1; m < 16; ++m) { cplx w = twA[PM(m) * 256 + t]; TWF(m, w); }
#pragma unroll
    for (int m = 0; m < 16; ++m) Z[SK(t + 256 * PM(m))] = packh(re[m], im[m]);
    __syncthreads();

    // ---- middle stages wave-private: wave w owns elements [1024w, 1024w+1024) ----
    const int j = t & 15;
    const int base = ((t >> 4) << 8) + j;

    // ---- fwd stage 2 (stride 16) ----
#pragma unroll
    for (int q = 0; q < 16; ++q) {
        h4 v = Z[SK(base + 16 * q)];
        re[q] = mk2((float)v.x, (float)v.y); im[q] = mk2((float)v.z, (float)v.w);
    }
    ip16<-1, false>(re, im);
#pragma unroll
    for (int m = 1; m < 16; ++m) { cplx w = twB[PM(m) * 16 + j]; TWF(m, w); }
    __builtin_amdgcn_wave_barrier();
#pragma unroll
    for (int m = 0; m < 16; ++m) Z[SK(base + 16 * PM(m))] = packh(re[m], im[m]);
    __builtin_amdgcn_wave_barrier();

    // ---- fwd stage 3 (contig) + scaled square + inv stage 1 (contig) ----
    {
        const int b3 = t * 16;
        const float s = 1.0f / 8192.0f;   // fold /4096 (ifft) and /2 (imag trick)
#pragma unroll
        for (int q = 0; q < 16; ++q) {
            h4 v = Z[SK(b3 + q)];
            re[q] = mk2((float)v.x, (float)v.y); im[q] = mk2((float)v.z, (float)v.w);
        }
        ip16<-1, false>(re, im);
#pragma unroll
        for (int m = 0; m < 16; ++m) {
            f2 r = re[m], i = im[m];
            re[m] = (r * r - i * i) * s;      // (re^2 - im^2) * s, both rows
            im[m] = (r * i) * (2.0f * s);     // 2*s*re*im, both rows
        }
        ip16<1, true>(re, im);
        __builtin_amdgcn_wave_barrier();
#pragma unroll
        for (int q = 0; q < 16; ++q) Z[SK(b3 + q)] = packh(re[q], im[q]);
        __builtin_amdgcn_wave_barrier();
    }

    // ---- inv stage 2 (stride 16): conj twiddle, inverse dft ----
#pragma unroll
    for (int q = 0; q < 16; ++q) {
        h4 v = Z[SK(base + 16 * q)];
        re[q] = mk2((float)v.x, (float)v.y); im[q] = mk2((float)v.z, (float)v.w);
    }
#pragma unroll
    for (int q = 1; q < 16; ++q) { cplx w = twB[q * 16 + j]; TWC(q, w); }
    ip16<1, false>(re, im);
    __builtin_amdgcn_wave_barrier();
#pragma unroll
    for (int m = 0; m < 16; ++m) Z[SK(base + 16 * PM(m))] = packh(re[m], im[m]);
    __syncthreads();   // next stage is stride-256: cross-wave

    // ---- inv stage 3 (stride 256) + coalesced store (normalization folded) ----
#pragma unroll
    for (int q = 0; q < 16; ++q) {
        h4 v = Z[SK(t + 256 * q)];
        re[q] = mk2((float)v.x, (float)v.y); im[q] = mk2((float)v.z, (float)v.w);
    }
#pragma unroll
    for (int q = 1; q < 16; ++q) { cplx w = twA[q * 256 + t]; TWC(q, w); }
    ip16<1, false>(re, im);
#pragma unroll
    for (int m = 0; m < 16; ++m) {
        int idx = t + 256 * PM(m);
        o0[idx] = im[m].x;
        o1[idx] = im[m].y;
    }
#undef TWF
#undef TWC
}

extern "C" void kernel_launch(void* const* d_in, const int* in_sizes, int n_in,
                              void* d_out, int out_size, void* d_ws, size_t ws_size,
                              hipStream_t stream) {
    const float* a = (const float*)d_in[0];
    const float* b = (const float*)d_in[1];
    float* out = (float*)d_out;
    cplx* twA = (cplx*)d_ws;              // 4096 cplx
    cplx* twB = twA + 4096;               // 256 cplx  (total 34 KB)
    const int B = in_sizes[0] / FFT_N;    // 8192 rows

    twiddle_init<<<17, NT, 0, stream>>>(twA, twB);        // 4352 entries
    circconv4096_kernel<<<B / 2, NT, 0, stream>>>(a, b, out, twA, twB);
}